// Round 2
// baseline (629.045 us; speedup 1.0000x reference)
//
#include <hip/hip_runtime.h>

// Composite-filter formulation:
//   out[o] = sum_{k=0..54} Cp[r][k] * x[n0 - k],
//     r = (2o+32) % 3, n0 = (2o+32-r)/3,
//     Cp[p][k] = C[p+3k], C[j] = sum_{m=0..50} b[m]*h[j-2m] (h zero outside [0,62])
// Exact for 50 <= o < n_out; head (o<50: u[t<0]=0) and tail (o>=n_out: u=0)
// handled by a reference-faithful slow path (146 outputs total).

#define TPB 256
#define RPT 6                     // outputs per thread
#define OTILE (TPB * RPT)         // 1536 outputs per block
#define XTILE 1080                // x floats staged per block (needs 1026+54)
#define NTAPS 55
#define CPSTRIDE 56               // phase-major coeff stride (float4-aligned)

__global__ void build_coeffs(const float* __restrict__ h,
                             const float* __restrict__ b,
                             float* __restrict__ cp) {
    for (int idx = threadIdx.x; idx < 3 * CPSTRIDE; idx += blockDim.x) {
        const int p = idx / CPSTRIDE;
        const int k = idx - p * CPSTRIDE;
        float acc = 0.0f;
        if (k < NTAPS) {
            const int j = p + 3 * k;
            for (int m = 0; m <= 50; ++m) {
                const int hi = j - 2 * m;
                if (hi >= 0 && hi <= 62) acc += b[m] * h[hi];
            }
        }
        cp[idx] = acc;
    }
}

__device__ __forceinline__ float slow_out(int o, const float* __restrict__ x,
                                          const float* __restrict__ h,
                                          const float* __restrict__ b,
                                          int n_in, int n_out) {
    float acc = 0.0f;
    for (int m = 0; m <= 50; ++m) {
        const int t = o - m;
        if (t < 0 || t >= n_out) continue;   // u is zero outside [0, n_out)
        const int s  = 2 * t + 32;           // s >= 32
        const int p0 = s % 3;
        const int q  = s / 3;
        float u = 0.0f;
        for (int i = 0; i <= 20; ++i) {
            const int xi = q - i;
            if (xi >= 0 && xi < n_in) u += h[p0 + 3 * i] * x[xi];
        }
        acc += b[m] * u;
    }
    return acc;
}

__global__ __launch_bounds__(TPB) void fused_fast(
    const float* __restrict__ x, const float* __restrict__ h,
    const float* __restrict__ b, const float* __restrict__ cp,
    float* __restrict__ out, int n_in, int n_out, int out_size)
{
    __shared__ float x_s[XTILE];

    const int tid = threadIdx.x;
    const int o0  = blockIdx.x * OTILE;          // multiple of 3
    const int Qb  = (2 * o0 + 30) / 3;           // exact (2*o0 % 3 == 0)
    const int n_tile0 = Qb - 54;                 // lowest x index needed

    // Stage x tile (zero-padded at array bounds)
    for (int i = tid; i < XTILE; i += TPB) {
        const int n = n_tile0 + i;
        x_s[i] = (n >= 0 && n < n_in) ? x[n] : 0.0f;
    }
    __syncthreads();

    // Register sliding window: xv[c] = x[Q_t - 54 + c], Q_t = Qb + 4*tid
    float xv[60];
    const float4* xs4 = (const float4*)(x_s + 4 * tid);   // 16B aligned
#pragma unroll
    for (int i = 0; i < 15; ++i) {
        const float4 v = xs4[i];
        xv[4 * i + 0] = v.x; xv[4 * i + 1] = v.y;
        xv[4 * i + 2] = v.z; xv[4 * i + 3] = v.w;
    }

    const float* __restrict__ c0 = cp + 0 * CPSTRIDE;  // phase 0 (o%3==2)
    const float* __restrict__ c1 = cp + 1 * CPSTRIDE;  // phase 1 (o%3==1)
    const float* __restrict__ c2 = cp + 2 * CPSTRIDE;  // phase 2 (o%3==0)

    float a0 = 0.f, a1 = 0.f, a2 = 0.f, a3 = 0.f, a4 = 0.f, a5 = 0.f;
#pragma unroll
    for (int k = 0; k < NTAPS; ++k) {
        const float cc0 = c0[k];   // uniform loads (scalar-cache eligible)
        const float cc1 = c1[k];
        const float cc2 = c2[k];
        a0 += cc2 * xv[54 - k];
        a1 += cc1 * xv[55 - k];
        a2 += cc0 * xv[56 - k];
        a3 += cc2 * xv[56 - k];
        a4 += cc1 * xv[57 - k];
        a5 += cc0 * xv[58 - k];
    }

    const int ob = o0 + RPT * tid;   // multiple of 3 -> phases (2,1,0,2,1,0)
    float accs[RPT] = {a0, a1, a2, a3, a4, a5};
#pragma unroll
    for (int d = 0; d < RPT; ++d) {
        const int o = ob + d;
        if (o < out_size) {
            float v = accs[d];
            if (o < 50 || o >= n_out)            // head/tail exact path
                v = slow_out(o, x, h, b, n_in, n_out);
            out[o] = v;
        }
    }
}

extern "C" void kernel_launch(void* const* d_in, const int* in_sizes, int n_in_arrs,
                              void* d_out, int out_size, void* d_ws, size_t ws_size,
                              hipStream_t stream) {
    const float* x = (const float*)d_in[0];
    const float* h = (const float*)d_in[1];
    const float* b = (const float*)d_in[2];
    float* out = (float*)d_out;
    float* cp  = (float*)d_ws;                       // needs 3*56*4 = 672 bytes

    const int n_in  = in_sizes[0];                   // 8388608
    const int n_out = (int)((long long)n_in * 3 / 2);// 12582912

    build_coeffs<<<1, 64, 0, stream>>>(h, b, cp);

    const int nblocks = (out_size + OTILE - 1) / OTILE;  // 8193
    fused_fast<<<nblocks, TPB, 0, stream>>>(x, h, b, cp, out, n_in, n_out, out_size);
}

// Round 3
// 303.167 us; speedup vs baseline: 2.0749x; 2.0749x over previous
//
#include <hip/hip_runtime.h>

// Composite-filter formulation:
//   out[o] = sum_{k=0..54} Cp[r][k] * x[n0 - k],
//     r = (2o+32) % 3, n0 = (2o+32-r)/3,
//     Cp[p][k] = C[p+3k], C[j] = sum_m b[m]*h[j-2m]
// Hot kernel covers 50 <= o < n_out; head (o<50) and tail (o>=n_out, u=0)
// are written by a tiny reference-faithful boundary kernel (146 outputs).
//
// R2 post-mortem: per-thread float xv[60] went to scratch (VGPR=44, occ 4.8%).
// R3: sliding window as three rotating NAMED float4s -> guaranteed registers.

#define TPB 256
#define RPT 6                     // outputs per thread
#define OTILE (TPB * RPT)         // 1536 outputs per block
#define XTILE 1080                // x floats staged per block
#define NTAPS 55
#define CPSTRIDE 56               // phase-major coeff stride (zero-padded, float4-aligned)

__global__ void build_coeffs(const float* __restrict__ h,
                             const float* __restrict__ b,
                             float* __restrict__ cp) {
    for (int idx = threadIdx.x; idx < 3 * CPSTRIDE; idx += blockDim.x) {
        const int p = idx / CPSTRIDE;
        const int k = idx - p * CPSTRIDE;
        float acc = 0.0f;
        if (k < NTAPS) {
            const int j = p + 3 * k;
            for (int m = 0; m <= 50; ++m) {
                const int hi = j - 2 * m;
                if (hi >= 0 && hi <= 62) acc += b[m] * h[hi];
            }
        }
        cp[idx] = acc;
    }
}

__device__ float slow_out(int o, const float* __restrict__ x,
                          const float* __restrict__ h,
                          const float* __restrict__ b,
                          int n_in, int n_out) {
    float acc = 0.0f;
    for (int m = 0; m <= 50; ++m) {
        const int t = o - m;
        if (t < 0 || t >= n_out) continue;
        const int s  = 2 * t + 32;
        const int p0 = s % 3;
        const int q  = s / 3;
        float u = 0.0f;
        for (int i = 0; i <= 20; ++i) {
            const int xi = q - i;
            if (xi >= 0 && xi < n_in) u += h[p0 + 3 * i] * x[xi];
        }
        acc += b[m] * u;
    }
    return acc;
}

__global__ void boundary_fix(const float* __restrict__ x, const float* __restrict__ h,
                             const float* __restrict__ b, float* __restrict__ out,
                             int n_in, int n_out, int out_size) {
    const int i = threadIdx.x;
    const int n_tail = out_size - n_out;      // 96
    if (i < 50) {
        out[i] = slow_out(i, x, h, b, n_in, n_out);
    } else if (i < 50 + n_tail) {
        const int o = n_out + (i - 50);
        out[o] = slow_out(o, x, h, b, n_in, n_out);
    }
}

__global__ __launch_bounds__(TPB) void fused_fast(
    const float* __restrict__ x, const float* __restrict__ cp,
    float* __restrict__ out, int n_in, int n_out)
{
    __shared__ float x_s[XTILE];

    const int tid = threadIdx.x;
    const int o0  = blockIdx.x * OTILE;          // multiple of 6
    const int Qb  = (2 * o0 + 30) / 3;           // exact (2*o0 % 3 == 0)
    const int n_tile0 = Qb - 54;                 // lowest x index needed

    for (int i = tid; i < XTILE; i += TPB) {
        const int n = n_tile0 + i;
        x_s[i] = (n >= 0 && n < n_in) ? x[n] : 0.0f;
    }
    __syncthreads();

    // Thread's x chunks: xs4[j] = x_s[4*tid + 4j .. +3], j in [0,14]
    const float4* xs4 = (const float4*)(x_s + 4 * tid);
    const float4* c2q = (const float4*)(cp + 2 * CPSTRIDE);  // phase 2 (o%3==0)
    const float4* c1q = (const float4*)(cp + 1 * CPSTRIDE);  // phase 1
    const float4* c0q = (const float4*)(cp + 0 * CPSTRIDE);  // phase 0

    float a0 = 0.f, a1 = 0.f, a2 = 0.f, a3 = 0.f, a4 = 0.f, a5 = 0.f;

    float4 hi = xs4[14];
    float4 mi = xs4[13];

#pragma unroll
    for (int g = 0; g < 13; ++g) {
        const float4 lo = xs4[12 - g];
        const float4 q2 = c2q[g];
        const float4 q1 = c1q[g];
        const float4 q0 = c0q[g];
        // k = 4g+0
        a0 += q2.x * mi.z;  a1 += q1.x * mi.w;  a2 += q0.x * hi.x;
        a3 += q2.x * hi.x;  a4 += q1.x * hi.y;  a5 += q0.x * hi.z;
        // k = 4g+1
        a0 += q2.y * mi.y;  a1 += q1.y * mi.z;  a2 += q0.y * mi.w;
        a3 += q2.y * mi.w;  a4 += q1.y * hi.x;  a5 += q0.y * hi.y;
        // k = 4g+2
        a0 += q2.z * mi.x;  a1 += q1.z * mi.y;  a2 += q0.z * mi.z;
        a3 += q2.z * mi.z;  a4 += q1.z * mi.w;  a5 += q0.z * hi.x;
        // k = 4g+3
        a0 += q2.w * lo.w;  a1 += q1.w * mi.x;  a2 += q0.w * mi.y;
        a3 += q2.w * mi.y;  a4 += q1.w * mi.z;  a5 += q0.w * mi.w;
        hi = mi; mi = lo;
    }
    {   // tail: k = 52, 53, 54  (chunks: hi=chunk1, mi=chunk0)
        const float4 q2 = c2q[13];
        const float4 q1 = c1q[13];
        const float4 q0 = c0q[13];
        a0 += q2.x * mi.z;  a1 += q1.x * mi.w;  a2 += q0.x * hi.x;
        a3 += q2.x * hi.x;  a4 += q1.x * hi.y;  a5 += q0.x * hi.z;
        a0 += q2.y * mi.y;  a1 += q1.y * mi.z;  a2 += q0.y * mi.w;
        a3 += q2.y * mi.w;  a4 += q1.y * hi.x;  a5 += q0.y * hi.y;
        a0 += q2.z * mi.x;  a1 += q1.z * mi.y;  a2 += q0.z * mi.z;
        a3 += q2.z * mi.z;  a4 += q1.z * mi.w;  a5 += q0.z * hi.x;
    }

    const int ob = o0 + RPT * tid;               // even, multiple of 3
    if (ob >= 50 && ob + 5 < n_out) {            // interior fast path
        float2* o2 = (float2*)(out + ob);        // ob even -> 8B aligned
        o2[0] = make_float2(a0, a1);
        o2[1] = make_float2(a2, a3);
        o2[2] = make_float2(a4, a5);
    } else {
        const float accs[RPT] = {a0, a1, a2, a3, a4, a5};
#pragma unroll
        for (int d = 0; d < RPT; ++d) {
            const int o = ob + d;
            if (o >= 50 && o < n_out) out[o] = accs[d];
        }
    }
}

extern "C" void kernel_launch(void* const* d_in, const int* in_sizes, int n_in_arrs,
                              void* d_out, int out_size, void* d_ws, size_t ws_size,
                              hipStream_t stream) {
    const float* x = (const float*)d_in[0];
    const float* h = (const float*)d_in[1];
    const float* b = (const float*)d_in[2];
    float* out = (float*)d_out;
    float* cp  = (float*)d_ws;                        // 3*56*4 = 672 bytes

    const int n_in  = in_sizes[0];                    // 8388608
    const int n_out = (int)((long long)n_in * 3 / 2); // 12582912

    build_coeffs<<<1, 64, 0, stream>>>(h, b, cp);

    const int nblocks = ((int)((long long)n_out) + OTILE - 1) / OTILE + 1; // cover n_out + tail block
    fused_fast<<<nblocks, TPB, 0, stream>>>(x, cp, out, n_in, n_out);
    boundary_fix<<<1, 192, 0, stream>>>(x, h, b, out, n_in, n_out, out_size);
}

// Round 4
// 135.986 us; speedup vs baseline: 4.6258x; 2.2294x over previous
//
#include <hip/hip_runtime.h>

// Composite-filter formulation:
//   out[o] = sum_{k=0..54} Cp[r][k] * x[n0 - k],
//     r = (2o+32) % 3, n0 = (2o+32-r)/3,
//     Cp[p][k] = C[p+3k], C[j] = sum_m b[m]*h[j-2m]
// fused_fast covers 50 <= o < n_out; boundary kernel covers o<50 and
// o>=n_out (u[t]=0 outside [0,n_out)) via parallel LDS two-phase eval.

#define TPB 256
#define RPT 6                     // outputs per thread
#define OTILE (TPB * RPT)         // 1536 outputs per block
#define XTILE 1080                // x floats staged per block
#define NTAPS 55
#define CPSTRIDE 56               // phase-major coeff stride (zero-padded, float4-aligned)

__global__ void build_coeffs(const float* __restrict__ h,
                             const float* __restrict__ b,
                             float* __restrict__ cp) {
    __shared__ float h_s[63];
    __shared__ float b_s[51];
    const int tid = threadIdx.x;
    if (tid < 63) h_s[tid] = h[tid];
    if (tid < 51) b_s[tid] = b[tid];
    __syncthreads();
    for (int idx = tid; idx < 3 * CPSTRIDE; idx += blockDim.x) {
        const int p = idx / CPSTRIDE;
        const int k = idx - p * CPSTRIDE;
        float acc = 0.0f;
        if (k < NTAPS) {
            const int j = p + 3 * k;
            for (int m = 0; m <= 50; ++m) {
                const int hi = j - 2 * m;
                if (hi >= 0 && hi <= 62) acc += b_s[m] * h_s[hi];
            }
        }
        cp[idx] = acc;
    }
}

// Two blocks: block 0 = head (o in [0,50)), block 1 = tail (o in [n_out, out_size)).
__global__ __launch_bounds__(128) void boundary_fix(
    const float* __restrict__ x, const float* __restrict__ h,
    const float* __restrict__ b, float* __restrict__ out,
    int n_in, int n_out, int out_size)
{
    __shared__ float h_s[63];
    __shared__ float b_s[51];
    __shared__ float x_s[64];
    __shared__ float u_s[50];

    const int tid = threadIdx.x;
    if (tid < 63) h_s[tid] = h[tid];
    if (tid < 51) b_s[tid] = b[tid];

    if (blockIdx.x == 0) {
        // ---- head ----
        // u[t], t in [0,49]: q = (2t+32)/3 in [10,43]; x indices q-i in [-10,43]
        if (tid < 44) x_s[tid] = (tid < n_in) ? x[tid] : 0.0f;
        __syncthreads();
        if (tid < 50) {
            const int s  = 2 * tid + 32;
            const int p0 = s % 3;
            const int q  = s / 3;
            float u = 0.0f;
            #pragma unroll
            for (int i = 0; i <= 20; ++i) {
                const int xi = q - i;
                u += h_s[p0 + 3 * i] * ((xi >= 0) ? x_s[xi] : 0.0f);
            }
            u_s[tid] = u;
        }
        __syncthreads();
        if (tid < 50) {
            // out[o] = sum_{t=0..o} b[o-t] * u[t]
            float acc = 0.0f;
            for (int t = 0; t <= tid; ++t) acc += b_s[tid - t] * u_s[t];
            out[tid] = acc;
        }
    } else {
        // ---- tail ----
        // u[t], t = n_out-50+j, j in [0,49]; q in [qmin, qmin+33]; x zero for xi>=n_in
        const int t0   = n_out - 50;
        const int qmin = (2 * t0 + 32) / 3;
        const int xb   = qmin - 20;
        if (tid < 64) {
            const int xi = xb + tid;
            x_s[tid] = (xi >= 0 && xi < n_in) ? x[xi] : 0.0f;
        }
        __syncthreads();
        if (tid < 50) {
            const int t  = t0 + tid;
            const int s  = 2 * t + 32;
            const int p0 = s % 3;
            const int q  = s / 3;
            const int base = q - xb;           // in [20, 63]
            float u = 0.0f;
            #pragma unroll
            for (int i = 0; i <= 20; ++i)
                u += h_s[p0 + 3 * i] * x_s[base - i];
            u_s[tid] = u;
        }
        __syncthreads();
        const int n_tail = out_size - n_out;   // 96
        if (tid < n_tail) {
            // out[n_out+d] = sum_{j=d}^{49} b[d+50-j] * u_s[j]   (empty -> 0)
            float acc = 0.0f;
            for (int j = tid; j <= 49; ++j) acc += b_s[tid + 50 - j] * u_s[j];
            out[n_out + tid] = acc;
        }
    }
}

__global__ __launch_bounds__(TPB) void fused_fast(
    const float* __restrict__ x, const float* __restrict__ cp,
    float* __restrict__ out, int n_in, int n_out)
{
    __shared__ float x_s[XTILE];

    const int tid = threadIdx.x;
    const int o0  = blockIdx.x * OTILE;          // multiple of 6
    const int Qb  = (2 * o0 + 30) / 3;           // exact (2*o0 % 3 == 0)
    const int n_tile0 = Qb - 54;                 // lowest x index needed

    for (int i = tid; i < XTILE; i += TPB) {
        const int n = n_tile0 + i;
        x_s[i] = (n >= 0 && n < n_in) ? x[n] : 0.0f;
    }
    __syncthreads();

    const float4* xs4 = (const float4*)(x_s + 4 * tid);
    const float4* c2q = (const float4*)(cp + 2 * CPSTRIDE);  // phase 2 (o%3==0)
    const float4* c1q = (const float4*)(cp + 1 * CPSTRIDE);
    const float4* c0q = (const float4*)(cp + 0 * CPSTRIDE);

    float a0 = 0.f, a1 = 0.f, a2 = 0.f, a3 = 0.f, a4 = 0.f, a5 = 0.f;

    float4 hi = xs4[14];
    float4 mi = xs4[13];

#pragma unroll
    for (int g = 0; g < 13; ++g) {
        const float4 lo = xs4[12 - g];
        const float4 q2 = c2q[g];
        const float4 q1 = c1q[g];
        const float4 q0 = c0q[g];
        a0 += q2.x * mi.z;  a1 += q1.x * mi.w;  a2 += q0.x * hi.x;
        a3 += q2.x * hi.x;  a4 += q1.x * hi.y;  a5 += q0.x * hi.z;
        a0 += q2.y * mi.y;  a1 += q1.y * mi.z;  a2 += q0.y * mi.w;
        a3 += q2.y * mi.w;  a4 += q1.y * hi.x;  a5 += q0.y * hi.y;
        a0 += q2.z * mi.x;  a1 += q1.z * mi.y;  a2 += q0.z * mi.z;
        a3 += q2.z * mi.z;  a4 += q1.z * mi.w;  a5 += q0.z * hi.x;
        a0 += q2.w * lo.w;  a1 += q1.w * mi.x;  a2 += q0.w * mi.y;
        a3 += q2.w * mi.y;  a4 += q1.w * mi.z;  a5 += q0.w * mi.w;
        hi = mi; mi = lo;
    }
    {   // tail: k = 52, 53, 54
        const float4 q2 = c2q[13];
        const float4 q1 = c1q[13];
        const float4 q0 = c0q[13];
        a0 += q2.x * mi.z;  a1 += q1.x * mi.w;  a2 += q0.x * hi.x;
        a3 += q2.x * hi.x;  a4 += q1.x * hi.y;  a5 += q0.x * hi.z;
        a0 += q2.y * mi.y;  a1 += q1.y * mi.z;  a2 += q0.y * mi.w;
        a3 += q2.y * mi.w;  a4 += q1.y * hi.x;  a5 += q0.y * hi.y;
        a0 += q2.z * mi.x;  a1 += q1.z * mi.y;  a2 += q0.z * mi.z;
        a3 += q2.z * mi.z;  a4 += q1.z * mi.w;  a5 += q0.z * hi.x;
    }

    const int ob = o0 + RPT * tid;
    if (ob >= 50 && ob + 5 < n_out) {
        float2* o2 = (float2*)(out + ob);
        o2[0] = make_float2(a0, a1);
        o2[1] = make_float2(a2, a3);
        o2[2] = make_float2(a4, a5);
    } else {
        const float accs[RPT] = {a0, a1, a2, a3, a4, a5};
#pragma unroll
        for (int d = 0; d < RPT; ++d) {
            const int o = ob + d;
            if (o >= 50 && o < n_out) out[o] = accs[d];
        }
    }
}

extern "C" void kernel_launch(void* const* d_in, const int* in_sizes, int n_in_arrs,
                              void* d_out, int out_size, void* d_ws, size_t ws_size,
                              hipStream_t stream) {
    const float* x = (const float*)d_in[0];
    const float* h = (const float*)d_in[1];
    const float* b = (const float*)d_in[2];
    float* out = (float*)d_out;
    float* cp  = (float*)d_ws;                        // 3*56*4 = 672 bytes

    const int n_in  = in_sizes[0];                    // 8388608
    const int n_out = (int)((long long)n_in * 3 / 2); // 12582912

    build_coeffs<<<1, 64, 0, stream>>>(h, b, cp);

    const int nblocks = (n_out + OTILE - 1) / OTILE + 1;
    fused_fast<<<nblocks, TPB, 0, stream>>>(x, cp, out, n_in, n_out);
    boundary_fix<<<2, 128, 0, stream>>>(x, h, b, out, n_in, n_out, out_size);
}